// Round 10
// baseline (495.870 us; speedup 1.0000x reference)
//
#include <hip/hip_runtime.h>

#define NN 32      // nodes
#define FF 64      // GAT out features
#define HH 128     // LSTM hidden
#define G4 512     // 4*H
#define BB 32      // batch
#define TT 512     // time steps
#define ET 128     // 96 edges + 32 self loops
#define NPOS (BB*TT)

__device__ __forceinline__ float frcp(float x) { return __builtin_amdgcn_rcpf(x); }

// ---------------- prep: fold GAT linear into LSTM input weights + Wt transpose ----------------
// W_eff[n,j] = sum_f w_gat[f]*W_ih[n*FF+f,j]; biasp[n,j] = sum_f b_gat[f]*W_ih[..]
// Wt[t*128 + m*16 + kk] = W_hh[( (t&7)*16 + kk )][ (m>>1)*128 + 2*(t>>3) + (m&1) ]
__global__ __launch_bounds__(512) void prep_kernel(const float* __restrict__ w_gat,
                                                   const float* __restrict__ b_gat,
                                                   const float* __restrict__ W_ih,
                                                   const float* __restrict__ W_hh,
                                                   float* __restrict__ W_eff,
                                                   float* __restrict__ biasp,
                                                   float* __restrict__ Wt) {
  int j = threadIdx.x;
  int n = blockIdx.x;
  float accw = 0.f, accb = 0.f;
#pragma unroll 8
  for (int f = 0; f < FF; ++f) {
    float wv = W_ih[(n * FF + f) * G4 + j];
    accw = fmaf(w_gat[f], wv, accw);
    accb = fmaf(b_gat[f], wv, accb);
  }
  W_eff[n * G4 + j] = accw;
  biasp[n * G4 + j] = accb;
  // fused weight transpose for the asm LSTM (4 elements per thread)
  int g0 = (n * G4 + j) * 4;
#pragma unroll
  for (int q = 0; q < 4; ++q) {
    int e = g0 + q;
    int t = e >> 7, idx = e & 127;
    int ko = t & 7, r2 = t >> 3;
    int m = idx >> 4, kk = idx & 15;
    int col = (m >> 1) * 128 + 2 * r2 + (m & 1);
    Wt[e] = W_hh[(ko * 16 + kk) * G4 + col];
  }
}

// ---------------- fused GAT + xw (+ block-local bias/sort/scal, was prep2) ----------------
__global__ __launch_bounds__(256) void gatxw_kernel(const float* __restrict__ x_seq,
                                                    const int* __restrict__ ei,
                                                    const float* __restrict__ w_gat,
                                                    const float* __restrict__ att_src,
                                                    const float* __restrict__ att_dst,
                                                    const float* __restrict__ b_ih,
                                                    const float* __restrict__ b_hh,
                                                    const float* __restrict__ W_eff,
                                                    const float* __restrict__ biasp,
                                                    float* __restrict__ xw) {
  __shared__ int srt[ET];
  __shared__ int offs[NN + 1];
  __shared__ int cnt[NN];
  __shared__ float xs[256];
  __shared__ float sl[256];
  __shared__ float scal_sh[2];
  int tid = threadIdx.x;
  int posbase = blockIdx.x * 8;
  float we0[NN], we1[NN];
#pragma unroll
  for (int nn = 0; nn < NN; ++nn) {
    we0[nn] = W_eff[nn * G4 + tid];
    we1[nn] = W_eff[nn * G4 + 256 + tid];
  }
  float b0 = b_ih[tid] + b_hh[tid];
  float b1 = b_ih[256 + tid] + b_hh[256 + tid];
#pragma unroll 8
  for (int n = 0; n < NN; ++n) {
    b0 += biasp[n * G4 + tid];
    b1 += biasp[n * G4 + 256 + tid];
  }
  if (tid < NN) cnt[tid] = 0;
  __syncthreads();
  int es = 0, ed = 0, tk = 0;
  if (tid < ET) {
    if (tid < 96) { es = ei[tid]; ed = ei[96 + tid]; }
    else { es = tid - 96; ed = tid - 96; }
    tk = atomicAdd(&cnt[ed], 1);
  }
  __syncthreads();
  if (tid == 0) {
    offs[0] = 0;
    for (int n = 0; n < NN; ++n) offs[n + 1] = offs[n] + cnt[n];
  }
  if (tid == 1) {
    float cs = 0.f, cd = 0.f;
    for (int f = 0; f < FF; ++f) {
      cs = fmaf(w_gat[f], att_src[f], cs);
      cd = fmaf(w_gat[f], att_dst[f], cd);
    }
    scal_sh[0] = cs;
    scal_sh[1] = cd;
  }
  __syncthreads();
  if (tid < ET) srt[offs[ed] + tk] = es;
  xs[tid] = x_seq[posbase * NN + tid];  // coalesced
  __syncthreads();
  float cs = scal_sh[0], cd = scal_sh[1];
  int p = tid >> 5, n = tid & 31;
  int base = p * 32;
  int e0 = offs[n], e1 = offs[n + 1];
  float xn = xs[base + n];
  float cdxn = cd * xn;
  float m = -3.0e38f;
  for (int e = e0; e < e1; ++e) {
    float ev = fmaf(cs, xs[base + srt[e]], cdxn);
    ev = ev > 0.f ? ev : 0.2f * ev;  // LeakyReLU(0.2)
    m = fmaxf(m, ev);
  }
  float z = 0.f, sa = 0.f;
  for (int e = e0; e < e1; ++e) {
    float xsv = xs[base + srt[e]];
    float ev = fmaf(cs, xsv, cdxn);
    ev = ev > 0.f ? ev : 0.2f * ev;
    float ex = __expf(ev - m);
    z += ex;
    sa = fmaf(ex, xsv, sa);
  }
  sl[p * 32 + n] = sa * frcp(z);
  __syncthreads();
  for (int pp = 0; pp < 8; ++pp) {
    const float4* sp = (const float4*)&sl[pp * 32];
    float a0 = b0, a1 = b1;
#pragma unroll
    for (int q = 0; q < 8; ++q) {
      float4 sv = sp[q];
      a0 = fmaf(sv.x, we0[4 * q], a0);
      a0 = fmaf(sv.y, we0[4 * q + 1], a0);
      a0 = fmaf(sv.z, we0[4 * q + 2], a0);
      a0 = fmaf(sv.w, we0[4 * q + 3], a0);
      a1 = fmaf(sv.x, we1[4 * q], a1);
      a1 = fmaf(sv.y, we1[4 * q + 1], a1);
      a1 = fmaf(sv.z, we1[4 * q + 2], a1);
      a1 = fmaf(sv.w, we1[4 * q + 3], a1);
    }
    size_t row = (size_t)(posbase + pp) * G4;
    xw[row + tid] = a0;
    xw[row + 256 + tid] = a1;
  }
}

// ---------------- LSTM scan: asm t-loop, C=8 columns/thread, ksplit=8 ----------------
// Thread (r2=tid>>3, ko=tid&7): rows {2r2, 2r2+1} x 4 gates, k in [16ko,16ko+16).
//  - h LDS layout: k-region ko at byte offset ko*80 (20-float stride): the 8
//    distinct b128 addresses per wave tile all 32 banks exactly -> conflict-free
//  - 4 ds_read_b128/thread (32 KB/step/CU vs 64 KB at C=4)
//  - 8-lane reduce in DPP: quad_perm xor1, quad_perm xor2, row_half_mirror
//  - x folded via 8 lane masks before the butterfly (one x load per lane/step)
//  - both rows' activations per thread (ILP); all 8 lanes write same b64 (free)

#define PK8F(HP, W0, W1, W2, W3, W4, W5, W6, W7) \
  "v_pk_fma_f32 v[48:49], v[" HP "], v[" W0 "], 0\n\t" \
  "v_pk_fma_f32 v[50:51], v[" HP "], v[" W1 "], 0\n\t" \
  "v_pk_fma_f32 v[52:53], v[" HP "], v[" W2 "], 0\n\t" \
  "v_pk_fma_f32 v[54:55], v[" HP "], v[" W3 "], 0\n\t" \
  "v_pk_fma_f32 v[56:57], v[" HP "], v[" W4 "], 0\n\t" \
  "v_pk_fma_f32 v[58:59], v[" HP "], v[" W5 "], 0\n\t" \
  "v_pk_fma_f32 v[60:61], v[" HP "], v[" W6 "], 0\n\t" \
  "v_pk_fma_f32 v[62:63], v[" HP "], v[" W7 "], 0\n\t"

#define PK8A(HP, W0, W1, W2, W3, W4, W5, W6, W7) \
  "v_pk_fma_f32 v[48:49], v[" HP "], v[" W0 "], v[48:49]\n\t" \
  "v_pk_fma_f32 v[50:51], v[" HP "], v[" W1 "], v[50:51]\n\t" \
  "v_pk_fma_f32 v[52:53], v[" HP "], v[" W2 "], v[52:53]\n\t" \
  "v_pk_fma_f32 v[54:55], v[" HP "], v[" W3 "], v[54:55]\n\t" \
  "v_pk_fma_f32 v[56:57], v[" HP "], v[" W4 "], v[56:57]\n\t" \
  "v_pk_fma_f32 v[58:59], v[" HP "], v[" W5 "], v[58:59]\n\t" \
  "v_pk_fma_f32 v[60:61], v[" HP "], v[" W6 "], v[60:61]\n\t" \
  "v_pk_fma_f32 v[62:63], v[" HP "], v[" W7 "], v[62:63]\n\t"

#define DPP8(CTRL) \
  "v_add_f32_dpp v208, v208, v208 " CTRL " row_mask:0xf bank_mask:0xf\n\t" \
  "v_add_f32_dpp v209, v209, v209 " CTRL " row_mask:0xf bank_mask:0xf\n\t" \
  "v_add_f32_dpp v210, v210, v210 " CTRL " row_mask:0xf bank_mask:0xf\n\t" \
  "v_add_f32_dpp v211, v211, v211 " CTRL " row_mask:0xf bank_mask:0xf\n\t" \
  "v_add_f32_dpp v212, v212, v212 " CTRL " row_mask:0xf bank_mask:0xf\n\t" \
  "v_add_f32_dpp v213, v213, v213 " CTRL " row_mask:0xf bank_mask:0xf\n\t" \
  "v_add_f32_dpp v214, v214, v214 " CTRL " row_mask:0xf bank_mask:0xf\n\t" \
  "v_add_f32_dpp v215, v215, v215 " CTRL " row_mask:0xf bank_mask:0xf\n\t"

#define PHASE(XSLOT, RD, WR) \
  "ds_read_b128 v[32:35], " RD "\n\t" \
  "ds_read_b128 v[36:39], " RD " offset:16\n\t" \
  "ds_read_b128 v[40:43], " RD " offset:32\n\t" \
  "ds_read_b128 v[44:47], " RD " offset:48\n\t" \
  "s_waitcnt vmcnt(3)\n\t" \
  "v_mov_b32 v192, " XSLOT "\n\t" \
  "global_load_dword " XSLOT ", v194, %[xwb]\n\t" \
  "v_add_u32 v194, 0x800, v194\n\t" \
  "s_waitcnt lgkmcnt(3)\n\t" \
  PK8F("32:33", "64:65", "80:81", "96:97", "112:113", "128:129", "144:145", "160:161", "176:177") \
  PK8A("34:35", "66:67", "82:83", "98:99", "114:115", "130:131", "146:147", "162:163", "178:179") \
  "s_waitcnt lgkmcnt(2)\n\t" \
  PK8A("36:37", "68:69", "84:85", "100:101", "116:117", "132:133", "148:149", "164:165", "180:181") \
  PK8A("38:39", "70:71", "86:87", "102:103", "118:119", "134:135", "150:151", "166:167", "182:183") \
  "s_waitcnt lgkmcnt(1)\n\t" \
  PK8A("40:41", "72:73", "88:89", "104:105", "120:121", "136:137", "152:153", "168:169", "184:185") \
  PK8A("42:43", "74:75", "90:91", "106:107", "122:123", "138:139", "154:155", "170:171", "186:187") \
  "s_waitcnt lgkmcnt(0)\n\t" \
  PK8A("44:45", "76:77", "92:93", "108:109", "124:125", "140:141", "156:157", "172:173", "188:189") \
  PK8A("46:47", "78:79", "94:95", "110:111", "126:127", "142:143", "158:159", "174:175", "190:191") \
  "v_add_f32 v208, v48, v49\n\t" \
  "v_add_f32 v209, v50, v51\n\t" \
  "v_add_f32 v210, v52, v53\n\t" \
  "v_add_f32 v211, v54, v55\n\t" \
  "v_add_f32 v212, v56, v57\n\t" \
  "v_add_f32 v213, v58, v59\n\t" \
  "v_add_f32 v214, v60, v61\n\t" \
  "v_add_f32 v215, v62, v63\n\t" \
  "v_fmac_f32 v208, v192, v200\n\t" \
  "v_fmac_f32 v209, v192, v201\n\t" \
  "v_fmac_f32 v210, v192, v202\n\t" \
  "v_fmac_f32 v211, v192, v203\n\t" \
  "v_fmac_f32 v212, v192, v204\n\t" \
  "v_fmac_f32 v213, v192, v205\n\t" \
  "v_fmac_f32 v214, v192, v206\n\t" \
  "v_fmac_f32 v215, v192, v207\n\t" \
  DPP8("quad_perm:[1,0,3,2]") \
  DPP8("quad_perm:[2,3,0,1]") \
  DPP8("row_half_mirror") \
  "v_mul_f32 v48, 0xbfb8aa3b, v208\n\t" \
  "v_mul_f32 v49, 0xbfb8aa3b, v209\n\t" \
  "v_mul_f32 v50, 0xbfb8aa3b, v210\n\t" \
  "v_mul_f32 v51, 0xbfb8aa3b, v211\n\t" \
  "v_mul_f32 v52, 0x4038aa3b, v212\n\t" \
  "v_mul_f32 v53, 0x4038aa3b, v213\n\t" \
  "v_mul_f32 v54, 0xbfb8aa3b, v214\n\t" \
  "v_mul_f32 v55, 0xbfb8aa3b, v215\n\t" \
  "v_exp_f32 v48, v48\n\t" \
  "v_exp_f32 v49, v49\n\t" \
  "v_exp_f32 v50, v50\n\t" \
  "v_exp_f32 v51, v51\n\t" \
  "v_exp_f32 v52, v52\n\t" \
  "v_exp_f32 v53, v53\n\t" \
  "v_exp_f32 v54, v54\n\t" \
  "v_exp_f32 v55, v55\n\t" \
  "v_add_f32 v48, 1.0, v48\n\t" \
  "v_add_f32 v49, 1.0, v49\n\t" \
  "v_add_f32 v50, 1.0, v50\n\t" \
  "v_add_f32 v51, 1.0, v51\n\t" \
  "v_add_f32 v52, 1.0, v52\n\t" \
  "v_add_f32 v53, 1.0, v53\n\t" \
  "v_add_f32 v54, 1.0, v54\n\t" \
  "v_add_f32 v55, 1.0, v55\n\t" \
  "v_rcp_f32 v48, v48\n\t" \
  "v_rcp_f32 v49, v49\n\t" \
  "v_rcp_f32 v50, v50\n\t" \
  "v_rcp_f32 v51, v51\n\t" \
  "v_rcp_f32 v52, v52\n\t" \
  "v_rcp_f32 v53, v53\n\t" \
  "v_rcp_f32 v54, v54\n\t" \
  "v_rcp_f32 v55, v55\n\t" \
  "v_fma_f32 v52, -2.0, v52, 1.0\n\t" \
  "v_fma_f32 v53, -2.0, v53, 1.0\n\t" \
  "v_mul_f32 v56, v48, v52\n\t" \
  "v_mul_f32 v57, v49, v53\n\t" \
  "v_fma_f32 v199, v50, v199, v56\n\t" \
  "v_fma_f32 v193, v51, v193, v57\n\t" \
  "v_mul_f32 v58, 0x4038aa3b, v199\n\t" \
  "v_mul_f32 v59, 0x4038aa3b, v193\n\t" \
  "v_exp_f32 v58, v58\n\t" \
  "v_exp_f32 v59, v59\n\t" \
  "s_nop 1\n\t" \
  "v_add_f32 v58, 1.0, v58\n\t" \
  "v_add_f32 v59, 1.0, v59\n\t" \
  "v_rcp_f32 v58, v58\n\t" \
  "v_rcp_f32 v59, v59\n\t" \
  "s_nop 1\n\t" \
  "v_fma_f32 v58, -2.0, v58, 1.0\n\t" \
  "v_fma_f32 v59, -2.0, v59, 1.0\n\t" \
  "v_mul_f32 v60, v54, v58\n\t" \
  "v_mul_f32 v61, v55, v59\n\t" \
  "ds_write_b64 " WR ", v[60:61]\n\t" \
  "s_waitcnt lgkmcnt(0)\n\t" \
  "s_barrier\n\t"

__global__ __launch_bounds__(512, 2) void lstm_kernel(const float* __restrict__ xw,
                                                      const float* __restrict__ Wt,
                                                      const float* __restrict__ W_fc,
                                                      const float* __restrict__ b_fc,
                                                      float* __restrict__ out) {
  __shared__ __align__(16) float lds[320];  // hA [0,160) floats, hB [160,320)
  int b = blockIdx.x, tid = threadIdx.x;
  int r2 = tid >> 3, ko = tid & 7;
  if (tid < 320) lds[tid] = 0.f;
  const float* xwb = xw + (size_t)b * TT * G4;
  unsigned xoff0 = (unsigned)((((ko >> 1) * 128) + 2 * r2 + (ko & 1)) * 4);  // t=0
  unsigned wtoff = (unsigned)(tid * 512);
  unsigned lbase = (unsigned)(uintptr_t)&lds[0];  // LDS aperture is 4GB-aligned
  unsigned rda = lbase + (unsigned)(ko * 80);     // region ko, 20-float stride
  unsigned rdb = rda + 640;
  unsigned wra = lbase + (unsigned)((((2 * r2) >> 4) * 20 + ((2 * r2) & 15)) * 4);
  unsigned wrb = wra + 640;
  float mh0 = (ko == 0) ? 1.f : 0.f;
  float mh1 = (ko == 1) ? 1.f : 0.f;
  float mh2 = (ko == 2) ? 1.f : 0.f;
  float mh3 = (ko == 3) ? 1.f : 0.f;
  float mh4 = (ko == 4) ? 1.f : 0.f;
  float mh5 = (ko == 5) ? 1.f : 0.f;
  float mh6 = (ko == 6) ? 1.f : 0.f;
  float mh7 = (ko == 7) ? 1.f : 0.f;
  __syncthreads();
  asm volatile(
    "v_mov_b32 v194, %[xo]\n\t"
    "v_mov_b32 v195, %[rda]\n\t"
    "v_mov_b32 v196, %[rdb]\n\t"
    "v_mov_b32 v197, %[wra]\n\t"
    "v_mov_b32 v198, %[wrb]\n\t"
    "v_mov_b32 v199, 0\n\t"   // cA
    "v_mov_b32 v193, 0\n\t"   // cB
    "v_mov_b32 v200, %[m0]\n\t"
    "v_mov_b32 v201, %[m1]\n\t"
    "v_mov_b32 v202, %[m2]\n\t"
    "v_mov_b32 v203, %[m3]\n\t"
    "v_mov_b32 v204, %[m4]\n\t"
    "v_mov_b32 v205, %[m5]\n\t"
    "v_mov_b32 v206, %[m6]\n\t"
    "v_mov_b32 v207, %[m7]\n\t"
    // x prefetch ring: t=0..3 -> v224..v227
    "global_load_dword v224, v194, %[xwb]\n\t"
    "v_add_u32 v194, 0x800, v194\n\t"
    "global_load_dword v225, v194, %[xwb]\n\t"
    "v_add_u32 v194, 0x800, v194\n\t"
    "global_load_dword v226, v194, %[xwb]\n\t"
    "v_add_u32 v194, 0x800, v194\n\t"
    "global_load_dword v227, v194, %[xwb]\n\t"
    "v_add_u32 v194, 0x800, v194\n\t"
    "global_load_dwordx4 v[64:67], %[wto], %[wtb] offset:0\n\t"
    "global_load_dwordx4 v[68:71], %[wto], %[wtb] offset:16\n\t"
    "global_load_dwordx4 v[72:75], %[wto], %[wtb] offset:32\n\t"
    "global_load_dwordx4 v[76:79], %[wto], %[wtb] offset:48\n\t"
    "global_load_dwordx4 v[80:83], %[wto], %[wtb] offset:64\n\t"
    "global_load_dwordx4 v[84:87], %[wto], %[wtb] offset:80\n\t"
    "global_load_dwordx4 v[88:91], %[wto], %[wtb] offset:96\n\t"
    "global_load_dwordx4 v[92:95], %[wto], %[wtb] offset:112\n\t"
    "global_load_dwordx4 v[96:99], %[wto], %[wtb] offset:128\n\t"
    "global_load_dwordx4 v[100:103], %[wto], %[wtb] offset:144\n\t"
    "global_load_dwordx4 v[104:107], %[wto], %[wtb] offset:160\n\t"
    "global_load_dwordx4 v[108:111], %[wto], %[wtb] offset:176\n\t"
    "global_load_dwordx4 v[112:115], %[wto], %[wtb] offset:192\n\t"
    "global_load_dwordx4 v[116:119], %[wto], %[wtb] offset:208\n\t"
    "global_load_dwordx4 v[120:123], %[wto], %[wtb] offset:224\n\t"
    "global_load_dwordx4 v[124:127], %[wto], %[wtb] offset:240\n\t"
    "global_load_dwordx4 v[128:131], %[wto], %[wtb] offset:256\n\t"
    "global_load_dwordx4 v[132:135], %[wto], %[wtb] offset:272\n\t"
    "global_load_dwordx4 v[136:139], %[wto], %[wtb] offset:288\n\t"
    "global_load_dwordx4 v[140:143], %[wto], %[wtb] offset:304\n\t"
    "global_load_dwordx4 v[144:147], %[wto], %[wtb] offset:320\n\t"
    "global_load_dwordx4 v[148:151], %[wto], %[wtb] offset:336\n\t"
    "global_load_dwordx4 v[152:155], %[wto], %[wtb] offset:352\n\t"
    "global_load_dwordx4 v[156:159], %[wto], %[wtb] offset:368\n\t"
    "global_load_dwordx4 v[160:163], %[wto], %[wtb] offset:384\n\t"
    "global_load_dwordx4 v[164:167], %[wto], %[wtb] offset:400\n\t"
    "global_load_dwordx4 v[168:171], %[wto], %[wtb] offset:416\n\t"
    "global_load_dwordx4 v[172:175], %[wto], %[wtb] offset:432\n\t"
    "global_load_dwordx4 v[176:179], %[wto], %[wtb] offset:448\n\t"
    "global_load_dwordx4 v[180:183], %[wto], %[wtb] offset:464\n\t"
    "global_load_dwordx4 v[184:187], %[wto], %[wtb] offset:480\n\t"
    "global_load_dwordx4 v[188:191], %[wto], %[wtb] offset:496\n\t"
    "s_waitcnt vmcnt(0)\n\t"
    "s_movk_i32 s20, 0x80\n\t"    // 128 iterations x 4 phases = 512 steps
    "L_lstm_%=:\n\t"
    PHASE("v224", "v195", "v198")   // t%4==0: read A, write B
    PHASE("v225", "v196", "v197")   // t%4==1: read B, write A
    PHASE("v226", "v195", "v198")   // t%4==2: read A, write B
    PHASE("v227", "v196", "v197")   // t%4==3: read B, write A
    "s_sub_u32 s20, s20, 1\n\t"
    "s_cmp_lg_u32 s20, 0\n\t"
    "s_cbranch_scc1 L_lstm_%=\n\t"
    "s_waitcnt vmcnt(0) lgkmcnt(0)\n\t"
    :
    : [xwb]"s"(xwb), [wtb]"s"(Wt), [wto]"v"(wtoff), [xo]"v"(xoff0),
      [rda]"v"(rda), [rdb]"v"(rdb), [wra]"v"(wra), [wrb]"v"(wrb),
      [m0]"v"(mh0), [m1]"v"(mh1), [m2]"v"(mh2), [m3]"v"(mh3),
      [m4]"v"(mh4), [m5]"v"(mh5), [m6]"v"(mh6), [m7]"v"(mh7)
    : "memory", "scc", "s20",
      "v32","v33","v34","v35","v36","v37","v38","v39",
      "v40","v41","v42","v43","v44","v45","v46","v47",
      "v48","v49","v50","v51","v52","v53","v54","v55",
      "v56","v57","v58","v59","v60","v61","v62","v63",
      "v64","v65","v66","v67","v68","v69","v70","v71",
      "v72","v73","v74","v75","v76","v77","v78","v79",
      "v80","v81","v82","v83","v84","v85","v86","v87",
      "v88","v89","v90","v91","v92","v93","v94","v95",
      "v96","v97","v98","v99","v100","v101","v102","v103",
      "v104","v105","v106","v107","v108","v109","v110","v111",
      "v112","v113","v114","v115","v116","v117","v118","v119",
      "v120","v121","v122","v123","v124","v125","v126","v127",
      "v128","v129","v130","v131","v132","v133","v134","v135",
      "v136","v137","v138","v139","v140","v141","v142","v143",
      "v144","v145","v146","v147","v148","v149","v150","v151",
      "v152","v153","v154","v155","v156","v157","v158","v159",
      "v160","v161","v162","v163","v164","v165","v166","v167",
      "v168","v169","v170","v171","v172","v173","v174","v175",
      "v176","v177","v178","v179","v180","v181","v182","v183",
      "v184","v185","v186","v187","v188","v189","v190","v191",
      "v192","v193","v194","v195","v196","v197","v198","v199",
      "v200","v201","v202","v203","v204","v205","v206","v207",
      "v208","v209","v210","v211","v212","v213","v214","v215",
      "v216","v217","v218","v219","v220","v221","v222","v223",
      "v224","v225","v226","v227");
  __syncthreads();
  // final h (t=511, phase%4==3 wrote buffer A): h[k] at lds[(k>>4)*20 + (k&15)]
  if (tid < 4) {
    float acc = b_fc[tid];
#pragma unroll 8
    for (int k = 0; k < HH; ++k)
      acc = fmaf(lds[(k >> 4) * 20 + (k & 15)], W_fc[k * 4 + tid], acc);
    out[b * 4 + tid] = acc;
  }
}

extern "C" void kernel_launch(void* const* d_in, const int* in_sizes, int n_in,
                              void* d_out, int out_size, void* d_ws, size_t ws_size,
                              hipStream_t stream) {
  const float* x_seq   = (const float*)d_in[0];
  const int*   ei      = (const int*)d_in[1];
  const float* w_gat   = (const float*)d_in[2];
  const float* att_src = (const float*)d_in[3];
  const float* att_dst = (const float*)d_in[4];
  const float* b_gat   = (const float*)d_in[5];
  const float* W_ih    = (const float*)d_in[6];
  const float* W_hh    = (const float*)d_in[7];
  const float* b_ih    = (const float*)d_in[8];
  const float* b_hh    = (const float*)d_in[9];
  const float* W_fc    = (const float*)d_in[10];
  const float* b_fc    = (const float*)d_in[11];

  float* ws = (float*)d_ws;
  float* Wt    = ws;                            // 512*128 = 65536 f (16B-aligned)
  float* xw    = Wt + 65536;                    // (16384+8)*512 f (pad rows: 4-deep prefetch)
  float* W_eff = xw + (size_t)(NPOS + 8) * G4;  // 32*512
  float* biasp = W_eff + NN * G4;               // 32*512

  prep_kernel<<<NN, G4, 0, stream>>>(w_gat, b_gat, W_ih, W_hh, W_eff, biasp, Wt);
  gatxw_kernel<<<NPOS / 8, 256, 0, stream>>>(x_seq, ei, w_gat, att_src, att_dst,
                                             b_ih, b_hh, W_eff, biasp, xw);
  lstm_kernel<<<BB, G4, 0, stream>>>(xw, Wt, W_fc, b_fc, (float*)d_out);
}

// Round 11
// 429.460 us; speedup vs baseline: 1.1546x; 1.1546x over previous
//
#include <hip/hip_runtime.h>

#define NN 32      // nodes
#define FF 64      // GAT out features
#define HH 128     // LSTM hidden
#define G4 512     // 4*H
#define BB 32      // batch
#define TT 512     // time steps
#define ET 128     // 96 edges + 32 self loops
#define NPOS (BB*TT)

__device__ __forceinline__ float frcp(float x) { return __builtin_amdgcn_rcpf(x); }

// ---------------- prep: fold GAT linear into LSTM input weights + Wt transpose ----------------
// Wt layout for lstm thread tid=r2*8+ko: 128 floats = [c(8)][kk(16)],
// col(c) = (c&3)*128 + 2*r2 + (c>>2), k = ko*16 + kk
__global__ __launch_bounds__(512) void prep_kernel(const float* __restrict__ w_gat,
                                                   const float* __restrict__ b_gat,
                                                   const float* __restrict__ W_ih,
                                                   const float* __restrict__ W_hh,
                                                   float* __restrict__ W_eff,
                                                   float* __restrict__ biasp,
                                                   float* __restrict__ Wt) {
  int j = threadIdx.x;
  int n = blockIdx.x;
  float accw = 0.f, accb = 0.f;
#pragma unroll 8
  for (int f = 0; f < FF; ++f) {
    float wv = W_ih[(n * FF + f) * G4 + j];
    accw = fmaf(w_gat[f], wv, accw);
    accb = fmaf(b_gat[f], wv, accb);
  }
  W_eff[n * G4 + j] = accw;
  biasp[n * G4 + j] = accb;
  int g0 = (n * G4 + j) * 4;
#pragma unroll
  for (int q = 0; q < 4; ++q) {
    int e = g0 + q;
    int tl = e >> 7, idx = e & 127;
    int r2 = tl >> 3, ko = tl & 7;
    int c = idx >> 4, kk = idx & 15;
    int row = 2 * r2 + (c >> 2);
    int col = (c & 3) * 128 + row;
    Wt[e] = W_hh[(ko * 16 + kk) * G4 + col];
  }
}

// ---------------- fused GAT + xw (+ block-local bias/sort/scal) ----------------
__global__ __launch_bounds__(256) void gatxw_kernel(const float* __restrict__ x_seq,
                                                    const int* __restrict__ ei,
                                                    const float* __restrict__ w_gat,
                                                    const float* __restrict__ att_src,
                                                    const float* __restrict__ att_dst,
                                                    const float* __restrict__ b_ih,
                                                    const float* __restrict__ b_hh,
                                                    const float* __restrict__ W_eff,
                                                    const float* __restrict__ biasp,
                                                    float* __restrict__ xw) {
  __shared__ int srt[ET];
  __shared__ int offs[NN + 1];
  __shared__ int cnt[NN];
  __shared__ float xs[256];
  __shared__ float sl[256];
  __shared__ float scal_sh[2];
  int tid = threadIdx.x;
  int posbase = blockIdx.x * 8;
  float we0[NN], we1[NN];
#pragma unroll
  for (int nn = 0; nn < NN; ++nn) {
    we0[nn] = W_eff[nn * G4 + tid];
    we1[nn] = W_eff[nn * G4 + 256 + tid];
  }
  float b0 = b_ih[tid] + b_hh[tid];
  float b1 = b_ih[256 + tid] + b_hh[256 + tid];
#pragma unroll 8
  for (int n = 0; n < NN; ++n) {
    b0 += biasp[n * G4 + tid];
    b1 += biasp[n * G4 + 256 + tid];
  }
  if (tid < NN) cnt[tid] = 0;
  __syncthreads();
  int es = 0, ed = 0, tk = 0;
  if (tid < ET) {
    if (tid < 96) { es = ei[tid]; ed = ei[96 + tid]; }
    else { es = tid - 96; ed = tid - 96; }
    tk = atomicAdd(&cnt[ed], 1);
  }
  __syncthreads();
  if (tid == 0) {
    offs[0] = 0;
    for (int n = 0; n < NN; ++n) offs[n + 1] = offs[n] + cnt[n];
  }
  if (tid == 1) {
    float cs = 0.f, cd = 0.f;
    for (int f = 0; f < FF; ++f) {
      cs = fmaf(w_gat[f], att_src[f], cs);
      cd = fmaf(w_gat[f], att_dst[f], cd);
    }
    scal_sh[0] = cs;
    scal_sh[1] = cd;
  }
  __syncthreads();
  if (tid < ET) srt[offs[ed] + tk] = es;
  xs[tid] = x_seq[posbase * NN + tid];  // coalesced
  __syncthreads();
  float cs = scal_sh[0], cd = scal_sh[1];
  int p = tid >> 5, n = tid & 31;
  int base = p * 32;
  int e0 = offs[n], e1 = offs[n + 1];
  float xn = xs[base + n];
  float cdxn = cd * xn;
  float m = -3.0e38f;
  for (int e = e0; e < e1; ++e) {
    float ev = fmaf(cs, xs[base + srt[e]], cdxn);
    ev = ev > 0.f ? ev : 0.2f * ev;  // LeakyReLU(0.2)
    m = fmaxf(m, ev);
  }
  float z = 0.f, sa = 0.f;
  for (int e = e0; e < e1; ++e) {
    float xsv = xs[base + srt[e]];
    float ev = fmaf(cs, xsv, cdxn);
    ev = ev > 0.f ? ev : 0.2f * ev;
    float ex = __expf(ev - m);
    z += ex;
    sa = fmaf(ex, xsv, sa);
  }
  sl[p * 32 + n] = sa * frcp(z);
  __syncthreads();
  for (int pp = 0; pp < 8; ++pp) {
    const float4* sp = (const float4*)&sl[pp * 32];
    float a0 = b0, a1 = b1;
#pragma unroll
    for (int q = 0; q < 8; ++q) {
      float4 sv = sp[q];
      a0 = fmaf(sv.x, we0[4 * q], a0);
      a0 = fmaf(sv.y, we0[4 * q + 1], a0);
      a0 = fmaf(sv.z, we0[4 * q + 2], a0);
      a0 = fmaf(sv.w, we0[4 * q + 3], a0);
      a1 = fmaf(sv.x, we1[4 * q], a1);
      a1 = fmaf(sv.y, we1[4 * q + 1], a1);
      a1 = fmaf(sv.z, we1[4 * q + 2], a1);
      a1 = fmaf(sv.w, we1[4 * q + 3], a1);
    }
    size_t row = (size_t)(posbase + pp) * G4;
    xw[row + tid] = a0;
    xw[row + 256 + tid] = a1;
  }
}

// ---------------- LSTM scan: asm, C=8 with split activation ----------------
// tid = r2*8+ko. 8-lane group owns rows {2r2, 2r2+1}. Thread: 8 cols
// (4 gates x 2 rows) x 16 k => 64 pk_fma, 4 ds_read_b128 (32/CU/step = half
// of R9's LDS delivery). Reduce: 2 butterfly rounds on 8 regs, cndmask routes
// rowA->quad0 / rowB->quad1, final xor2 round on 4 regs. ONE activation per
// lane (10 trans vs R10's 20). h layout: region ko at 20-float stride
// (conflict-free, R10-verified). x ring vmcnt(3), ping-pong via offset:640.
// Regs: v[32:47] h, v[64:191] w, v[192:207] acc, v[208:215] sums,
// v[216:223] gates/act, v[224:227] x ring, v[228:235] masks, v236 xaddr,
// v237 rd base, v238 wr base, v239 c, v240 x cur.

#define PK8F(HP, W0, W1, W2, W3, W4, W5, W6, W7) \
  "v_pk_fma_f32 v[192:193], v[" HP "], v[" W0 "], 0\n\t" \
  "v_pk_fma_f32 v[194:195], v[" HP "], v[" W1 "], 0\n\t" \
  "v_pk_fma_f32 v[196:197], v[" HP "], v[" W2 "], 0\n\t" \
  "v_pk_fma_f32 v[198:199], v[" HP "], v[" W3 "], 0\n\t" \
  "v_pk_fma_f32 v[200:201], v[" HP "], v[" W4 "], 0\n\t" \
  "v_pk_fma_f32 v[202:203], v[" HP "], v[" W5 "], 0\n\t" \
  "v_pk_fma_f32 v[204:205], v[" HP "], v[" W6 "], 0\n\t" \
  "v_pk_fma_f32 v[206:207], v[" HP "], v[" W7 "], 0\n\t"

#define PK8A(HP, W0, W1, W2, W3, W4, W5, W6, W7) \
  "v_pk_fma_f32 v[192:193], v[" HP "], v[" W0 "], v[192:193]\n\t" \
  "v_pk_fma_f32 v[194:195], v[" HP "], v[" W1 "], v[194:195]\n\t" \
  "v_pk_fma_f32 v[196:197], v[" HP "], v[" W2 "], v[196:197]\n\t" \
  "v_pk_fma_f32 v[198:199], v[" HP "], v[" W3 "], v[198:199]\n\t" \
  "v_pk_fma_f32 v[200:201], v[" HP "], v[" W4 "], v[200:201]\n\t" \
  "v_pk_fma_f32 v[202:203], v[" HP "], v[" W5 "], v[202:203]\n\t" \
  "v_pk_fma_f32 v[204:205], v[" HP "], v[" W6 "], v[204:205]\n\t" \
  "v_pk_fma_f32 v[206:207], v[" HP "], v[" W7 "], v[206:207]\n\t"

#define DPP8(CTRL) \
  "v_add_f32_dpp v208, v208, v208 " CTRL " row_mask:0xf bank_mask:0xf\n\t" \
  "v_add_f32_dpp v209, v209, v209 " CTRL " row_mask:0xf bank_mask:0xf\n\t" \
  "v_add_f32_dpp v210, v210, v210 " CTRL " row_mask:0xf bank_mask:0xf\n\t" \
  "v_add_f32_dpp v211, v211, v211 " CTRL " row_mask:0xf bank_mask:0xf\n\t" \
  "v_add_f32_dpp v212, v212, v212 " CTRL " row_mask:0xf bank_mask:0xf\n\t" \
  "v_add_f32_dpp v213, v213, v213 " CTRL " row_mask:0xf bank_mask:0xf\n\t" \
  "v_add_f32_dpp v214, v214, v214 " CTRL " row_mask:0xf bank_mask:0xf\n\t" \
  "v_add_f32_dpp v215, v215, v215 " CTRL " row_mask:0xf bank_mask:0xf\n\t"

#define PHASE(XSLOT, O0, O1, O2, O3, WO) \
  "ds_read_b128 v[32:35], v237 offset:" O0 "\n\t" \
  "ds_read_b128 v[36:39], v237 offset:" O1 "\n\t" \
  "ds_read_b128 v[40:43], v237 offset:" O2 "\n\t" \
  "ds_read_b128 v[44:47], v237 offset:" O3 "\n\t" \
  "s_waitcnt vmcnt(3)\n\t" \
  "v_mov_b32 v240, " XSLOT "\n\t" \
  "global_load_dword " XSLOT ", v236, %[xwb]\n\t" \
  "v_add_u32 v236, 0x800, v236\n\t" \
  "s_waitcnt lgkmcnt(3)\n\t" \
  PK8F("32:33", "64:65", "80:81", "96:97", "112:113", "128:129", "144:145", "160:161", "176:177") \
  PK8A("34:35", "66:67", "82:83", "98:99", "114:115", "130:131", "146:147", "162:163", "178:179") \
  "s_waitcnt lgkmcnt(2)\n\t" \
  PK8A("36:37", "68:69", "84:85", "100:101", "116:117", "132:133", "148:149", "164:165", "180:181") \
  PK8A("38:39", "70:71", "86:87", "102:103", "118:119", "134:135", "150:151", "166:167", "182:183") \
  "s_waitcnt lgkmcnt(1)\n\t" \
  PK8A("40:41", "72:73", "88:89", "104:105", "120:121", "136:137", "152:153", "168:169", "184:185") \
  PK8A("42:43", "74:75", "90:91", "106:107", "122:123", "138:139", "154:155", "170:171", "186:187") \
  "s_waitcnt lgkmcnt(0)\n\t" \
  PK8A("44:45", "76:77", "92:93", "108:109", "124:125", "140:141", "156:157", "172:173", "188:189") \
  PK8A("46:47", "78:79", "94:95", "110:111", "126:127", "142:143", "158:159", "174:175", "190:191") \
  "v_add_f32 v208, v192, v193\n\t" \
  "v_add_f32 v209, v194, v195\n\t" \
  "v_add_f32 v210, v196, v197\n\t" \
  "v_add_f32 v211, v198, v199\n\t" \
  "v_add_f32 v212, v200, v201\n\t" \
  "v_add_f32 v213, v202, v203\n\t" \
  "v_add_f32 v214, v204, v205\n\t" \
  "v_add_f32 v215, v206, v207\n\t" \
  "v_fmac_f32 v208, v240, v228\n\t" \
  "v_fmac_f32 v209, v240, v229\n\t" \
  "v_fmac_f32 v210, v240, v230\n\t" \
  "v_fmac_f32 v211, v240, v231\n\t" \
  "v_fmac_f32 v212, v240, v232\n\t" \
  "v_fmac_f32 v213, v240, v233\n\t" \
  "v_fmac_f32 v214, v240, v234\n\t" \
  "v_fmac_f32 v215, v240, v235\n\t" \
  DPP8("row_half_mirror") \
  DPP8("quad_perm:[1,0,3,2]") \
  "v_cndmask_b32 v216, v212, v208, s[22:23]\n\t" \
  "v_cndmask_b32 v217, v213, v209, s[22:23]\n\t" \
  "v_cndmask_b32 v218, v214, v210, s[22:23]\n\t" \
  "v_cndmask_b32 v219, v215, v211, s[22:23]\n\t" \
  "v_add_f32_dpp v216, v216, v216 quad_perm:[2,3,0,1] row_mask:0xf bank_mask:0xf\n\t" \
  "v_add_f32_dpp v217, v217, v217 quad_perm:[2,3,0,1] row_mask:0xf bank_mask:0xf\n\t" \
  "v_add_f32_dpp v218, v218, v218 quad_perm:[2,3,0,1] row_mask:0xf bank_mask:0xf\n\t" \
  "v_add_f32_dpp v219, v219, v219 quad_perm:[2,3,0,1] row_mask:0xf bank_mask:0xf\n\t" \
  "v_mul_f32 v220, 0xbfb8aa3b, v216\n\t" \
  "v_mul_f32 v221, 0xbfb8aa3b, v217\n\t" \
  "v_mul_f32 v222, 0x4038aa3b, v218\n\t" \
  "v_mul_f32 v223, 0xbfb8aa3b, v219\n\t" \
  "v_exp_f32 v220, v220\n\t" \
  "v_exp_f32 v221, v221\n\t" \
  "v_exp_f32 v222, v222\n\t" \
  "v_exp_f32 v223, v223\n\t" \
  "v_add_f32 v220, 1.0, v220\n\t" \
  "v_add_f32 v221, 1.0, v221\n\t" \
  "v_add_f32 v222, 1.0, v222\n\t" \
  "v_add_f32 v223, 1.0, v223\n\t" \
  "v_rcp_f32 v220, v220\n\t" \
  "v_rcp_f32 v221, v221\n\t" \
  "v_rcp_f32 v222, v222\n\t" \
  "v_rcp_f32 v223, v223\n\t" \
  "v_fma_f32 v222, -2.0, v222, 1.0\n\t" \
  "v_mul_f32 v220, v220, v222\n\t" \
  "v_fma_f32 v239, v221, v239, v220\n\t" \
  "v_mul_f32 v221, 0x4038aa3b, v239\n\t" \
  "v_exp_f32 v221, v221\n\t" \
  "s_nop 1\n\t" \
  "v_add_f32 v221, 1.0, v221\n\t" \
  "v_rcp_f32 v221, v221\n\t" \
  "s_nop 1\n\t" \
  "v_fma_f32 v221, -2.0, v221, 1.0\n\t" \
  "v_mul_f32 v220, v223, v221\n\t" \
  "ds_write_b32 v238, v220 offset:" WO "\n\t" \
  "s_waitcnt lgkmcnt(0)\n\t" \
  "s_barrier\n\t"

__global__ __launch_bounds__(512, 2) void lstm_kernel(const float* __restrict__ xw,
                                                      const float* __restrict__ Wt,
                                                      const float* __restrict__ W_fc,
                                                      const float* __restrict__ b_fc,
                                                      float* __restrict__ out) {
  __shared__ __align__(16) float lds[320];  // hA [0,160) floats, hB [160,320)
  int b = blockIdx.x, tid = threadIdx.x;
  int r2 = tid >> 3, ko = tid & 7;
  if (tid < 320) lds[tid] = 0.f;
  const float* xwb = xw + (size_t)b * TT * G4;
  int myrow = 2 * r2 + (ko >> 2);
  unsigned xoff0 = (unsigned)((((ko & 3) * 128) + myrow) * 4);  // t=0
  unsigned wtoff = (unsigned)(tid * 512);
  unsigned lbase = (unsigned)(uintptr_t)&lds[0];  // LDS aperture is 4GB-aligned
  unsigned rda = lbase + (unsigned)(ko * 80);     // region ko, 20-float stride
  unsigned wra = lbase + (unsigned)(((myrow >> 4) * 20 + (myrow & 15)) * 4);
  float mh0 = (ko == 0) ? 1.f : 0.f;
  float mh1 = (ko == 1) ? 1.f : 0.f;
  float mh2 = (ko == 2) ? 1.f : 0.f;
  float mh3 = (ko == 3) ? 1.f : 0.f;
  float mh4 = (ko == 4) ? 1.f : 0.f;
  float mh5 = (ko == 5) ? 1.f : 0.f;
  float mh6 = (ko == 6) ? 1.f : 0.f;
  float mh7 = (ko == 7) ? 1.f : 0.f;
  unsigned q0 = (ko < 4) ? 1u : 0u;
  __syncthreads();
  asm volatile(
    "v_mov_b32 v236, %[xo]\n\t"
    "v_mov_b32 v237, %[rda]\n\t"
    "v_mov_b32 v238, %[wra]\n\t"
    "v_mov_b32 v239, 0\n\t"
    "v_mov_b32 v228, %[m0]\n\t"
    "v_mov_b32 v229, %[m1]\n\t"
    "v_mov_b32 v230, %[m2]\n\t"
    "v_mov_b32 v231, %[m3]\n\t"
    "v_mov_b32 v232, %[m4]\n\t"
    "v_mov_b32 v233, %[m5]\n\t"
    "v_mov_b32 v234, %[m6]\n\t"
    "v_mov_b32 v235, %[m7]\n\t"
    "v_cmp_eq_u32 s[22:23], 1, %[q0]\n\t"
    // x prefetch ring: t=0..3 -> v224..v227
    "global_load_dword v224, v236, %[xwb]\n\t"
    "v_add_u32 v236, 0x800, v236\n\t"
    "global_load_dword v225, v236, %[xwb]\n\t"
    "v_add_u32 v236, 0x800, v236\n\t"
    "global_load_dword v226, v236, %[xwb]\n\t"
    "v_add_u32 v236, 0x800, v236\n\t"
    "global_load_dword v227, v236, %[xwb]\n\t"
    "v_add_u32 v236, 0x800, v236\n\t"
    "global_load_dwordx4 v[64:67], %[wto], %[wtb] offset:0\n\t"
    "global_load_dwordx4 v[68:71], %[wto], %[wtb] offset:16\n\t"
    "global_load_dwordx4 v[72:75], %[wto], %[wtb] offset:32\n\t"
    "global_load_dwordx4 v[76:79], %[wto], %[wtb] offset:48\n\t"
    "global_load_dwordx4 v[80:83], %[wto], %[wtb] offset:64\n\t"
    "global_load_dwordx4 v[84:87], %[wto], %[wtb] offset:80\n\t"
    "global_load_dwordx4 v[88:91], %[wto], %[wtb] offset:96\n\t"
    "global_load_dwordx4 v[92:95], %[wto], %[wtb] offset:112\n\t"
    "global_load_dwordx4 v[96:99], %[wto], %[wtb] offset:128\n\t"
    "global_load_dwordx4 v[100:103], %[wto], %[wtb] offset:144\n\t"
    "global_load_dwordx4 v[104:107], %[wto], %[wtb] offset:160\n\t"
    "global_load_dwordx4 v[108:111], %[wto], %[wtb] offset:176\n\t"
    "global_load_dwordx4 v[112:115], %[wto], %[wtb] offset:192\n\t"
    "global_load_dwordx4 v[116:119], %[wto], %[wtb] offset:208\n\t"
    "global_load_dwordx4 v[120:123], %[wto], %[wtb] offset:224\n\t"
    "global_load_dwordx4 v[124:127], %[wto], %[wtb] offset:240\n\t"
    "global_load_dwordx4 v[128:131], %[wto], %[wtb] offset:256\n\t"
    "global_load_dwordx4 v[132:135], %[wto], %[wtb] offset:272\n\t"
    "global_load_dwordx4 v[136:139], %[wto], %[wtb] offset:288\n\t"
    "global_load_dwordx4 v[140:143], %[wto], %[wtb] offset:304\n\t"
    "global_load_dwordx4 v[144:147], %[wto], %[wtb] offset:320\n\t"
    "global_load_dwordx4 v[148:151], %[wto], %[wtb] offset:336\n\t"
    "global_load_dwordx4 v[152:155], %[wto], %[wtb] offset:352\n\t"
    "global_load_dwordx4 v[156:159], %[wto], %[wtb] offset:368\n\t"
    "global_load_dwordx4 v[160:163], %[wto], %[wtb] offset:384\n\t"
    "global_load_dwordx4 v[164:167], %[wto], %[wtb] offset:400\n\t"
    "global_load_dwordx4 v[168:171], %[wto], %[wtb] offset:416\n\t"
    "global_load_dwordx4 v[172:175], %[wto], %[wtb] offset:432\n\t"
    "global_load_dwordx4 v[176:179], %[wto], %[wtb] offset:448\n\t"
    "global_load_dwordx4 v[180:183], %[wto], %[wtb] offset:464\n\t"
    "global_load_dwordx4 v[184:187], %[wto], %[wtb] offset:480\n\t"
    "global_load_dwordx4 v[188:191], %[wto], %[wtb] offset:496\n\t"
    "s_waitcnt vmcnt(0)\n\t"
    "s_movk_i32 s20, 0x80\n\t"    // 128 iterations x 4 phases = 512 steps
    "L_lstm_%=:\n\t"
    PHASE("v224", "0",   "16",  "32",  "48",  "640")   // read A, write B
    PHASE("v225", "640", "656", "672", "688", "0")     // read B, write A
    PHASE("v226", "0",   "16",  "32",  "48",  "640")
    PHASE("v227", "640", "656", "672", "688", "0")
    "s_sub_u32 s20, s20, 1\n\t"
    "s_cmp_lg_u32 s20, 0\n\t"
    "s_cbranch_scc1 L_lstm_%=\n\t"
    "s_waitcnt vmcnt(0) lgkmcnt(0)\n\t"
    :
    : [xwb]"s"(xwb), [wtb]"s"(Wt), [wto]"v"(wtoff), [xo]"v"(xoff0),
      [rda]"v"(rda), [wra]"v"(wra), [q0]"v"(q0),
      [m0]"v"(mh0), [m1]"v"(mh1), [m2]"v"(mh2), [m3]"v"(mh3),
      [m4]"v"(mh4), [m5]"v"(mh5), [m6]"v"(mh6), [m7]"v"(mh7)
    : "memory", "scc", "s20", "s22", "s23",
      "v32","v33","v34","v35","v36","v37","v38","v39",
      "v40","v41","v42","v43","v44","v45","v46","v47",
      "v64","v65","v66","v67","v68","v69","v70","v71",
      "v72","v73","v74","v75","v76","v77","v78","v79",
      "v80","v81","v82","v83","v84","v85","v86","v87",
      "v88","v89","v90","v91","v92","v93","v94","v95",
      "v96","v97","v98","v99","v100","v101","v102","v103",
      "v104","v105","v106","v107","v108","v109","v110","v111",
      "v112","v113","v114","v115","v116","v117","v118","v119",
      "v120","v121","v122","v123","v124","v125","v126","v127",
      "v128","v129","v130","v131","v132","v133","v134","v135",
      "v136","v137","v138","v139","v140","v141","v142","v143",
      "v144","v145","v146","v147","v148","v149","v150","v151",
      "v152","v153","v154","v155","v156","v157","v158","v159",
      "v160","v161","v162","v163","v164","v165","v166","v167",
      "v168","v169","v170","v171","v172","v173","v174","v175",
      "v176","v177","v178","v179","v180","v181","v182","v183",
      "v184","v185","v186","v187","v188","v189","v190","v191",
      "v192","v193","v194","v195","v196","v197","v198","v199",
      "v200","v201","v202","v203","v204","v205","v206","v207",
      "v208","v209","v210","v211","v212","v213","v214","v215",
      "v216","v217","v218","v219","v220","v221","v222","v223",
      "v224","v225","v226","v227","v228","v229","v230","v231",
      "v232","v233","v234","v235","v236","v237","v238","v239","v240");
  __syncthreads();
  // final h (t=511 wrote buffer A): h[k] at lds[(k>>4)*20 + (k&15)]
  if (tid < 4) {
    float acc = b_fc[tid];
#pragma unroll 8
    for (int k = 0; k < HH; ++k)
      acc = fmaf(lds[(k >> 4) * 20 + (k & 15)], W_fc[k * 4 + tid], acc);
    out[b * 4 + tid] = acc;
  }
}

extern "C" void kernel_launch(void* const* d_in, const int* in_sizes, int n_in,
                              void* d_out, int out_size, void* d_ws, size_t ws_size,
                              hipStream_t stream) {
  const float* x_seq   = (const float*)d_in[0];
  const int*   ei      = (const int*)d_in[1];
  const float* w_gat   = (const float*)d_in[2];
  const float* att_src = (const float*)d_in[3];
  const float* att_dst = (const float*)d_in[4];
  const float* b_gat   = (const float*)d_in[5];
  const float* W_ih    = (const float*)d_in[6];
  const float* W_hh    = (const float*)d_in[7];
  const float* b_ih    = (const float*)d_in[8];
  const float* b_hh    = (const float*)d_in[9];
  const float* W_fc    = (const float*)d_in[10];
  const float* b_fc    = (const float*)d_in[11];

  float* ws = (float*)d_ws;
  float* Wt    = ws;                            // 512*128 = 65536 f (16B-aligned)
  float* xw    = Wt + 65536;                    // (16384+8)*512 f (pad rows: 4-deep prefetch)
  float* W_eff = xw + (size_t)(NPOS + 8) * G4;  // 32*512
  float* biasp = W_eff + NN * G4;               // 32*512

  prep_kernel<<<NN, G4, 0, stream>>>(w_gat, b_gat, W_ih, W_hh, W_eff, biasp, Wt);
  gatxw_kernel<<<NPOS / 8, 256, 0, stream>>>(x_seq, ei, w_gat, att_src, att_dst,
                                             b_ih, b_hh, W_eff, biasp, xw);
  lstm_kernel<<<BB, G4, 0, stream>>>(xw, Wt, W_fc, b_fc, (float*)d_out);
}

// Round 13
// 377.183 us; speedup vs baseline: 1.3147x; 1.1386x over previous
//
#include <hip/hip_runtime.h>

#define NN 32      // nodes
#define FF 64      // GAT out features
#define HH 128     // LSTM hidden
#define G4 512     // 4*H
#define BB 32      // batch
#define TT 512     // time steps
#define ET 128     // 96 edges + 32 self loops
#define NPOS (BB*TT)

__device__ __forceinline__ float frcp(float x) { return __builtin_amdgcn_rcpf(x); }

// ---------------- prep: fold GAT linear into LSTM input weights + Wt transpose ----------------
// R9 weight layout: Wt[tid*128 + g*32 + kk] = W_hh[(kq*32+kk)][g*128 + r], tid=r*4+kq
__global__ __launch_bounds__(512) void prep_kernel(const float* __restrict__ w_gat,
                                                   const float* __restrict__ b_gat,
                                                   const float* __restrict__ W_ih,
                                                   const float* __restrict__ W_hh,
                                                   float* __restrict__ W_eff,
                                                   float* __restrict__ biasp,
                                                   float* __restrict__ Wt) {
  int j = threadIdx.x;
  int n = blockIdx.x;
  float accw = 0.f, accb = 0.f;
#pragma unroll 8
  for (int f = 0; f < FF; ++f) {
    float wv = W_ih[(n * FF + f) * G4 + j];
    accw = fmaf(w_gat[f], wv, accw);
    accb = fmaf(b_gat[f], wv, accb);
  }
  W_eff[n * G4 + j] = accw;
  biasp[n * G4 + j] = accb;
  int g0 = (n * G4 + j) * 4;
#pragma unroll
  for (int q = 0; q < 4; ++q) {
    int e = g0 + q;
    int tl = e >> 7, idx = e & 127;
    int r = tl >> 2, kq = tl & 3;
    int g = idx >> 5, kk = idx & 31;
    Wt[e] = W_hh[(kq * 32 + kk) * G4 + g * 128 + r];
  }
}

// ---------------- fused GAT + xw (+ block-local bias/sort/scal) ----------------
__global__ __launch_bounds__(256) void gatxw_kernel(const float* __restrict__ x_seq,
                                                    const int* __restrict__ ei,
                                                    const float* __restrict__ w_gat,
                                                    const float* __restrict__ att_src,
                                                    const float* __restrict__ att_dst,
                                                    const float* __restrict__ b_ih,
                                                    const float* __restrict__ b_hh,
                                                    const float* __restrict__ W_eff,
                                                    const float* __restrict__ biasp,
                                                    float* __restrict__ xw) {
  __shared__ int srt[ET];
  __shared__ int offs[NN + 1];
  __shared__ int cnt[NN];
  __shared__ float xs[256];
  __shared__ float sl[256];
  __shared__ float scal_sh[2];
  int tid = threadIdx.x;
  int posbase = blockIdx.x * 8;
  float we0[NN], we1[NN];
#pragma unroll
  for (int nn = 0; nn < NN; ++nn) {
    we0[nn] = W_eff[nn * G4 + tid];
    we1[nn] = W_eff[nn * G4 + 256 + tid];
  }
  float b0 = b_ih[tid] + b_hh[tid];
  float b1 = b_ih[256 + tid] + b_hh[256 + tid];
#pragma unroll 8
  for (int n = 0; n < NN; ++n) {
    b0 += biasp[n * G4 + tid];
    b1 += biasp[n * G4 + 256 + tid];
  }
  if (tid < NN) cnt[tid] = 0;
  __syncthreads();
  int es = 0, ed = 0, tk = 0;
  if (tid < ET) {
    if (tid < 96) { es = ei[tid]; ed = ei[96 + tid]; }
    else { es = tid - 96; ed = tid - 96; }
    tk = atomicAdd(&cnt[ed], 1);
  }
  __syncthreads();
  if (tid == 0) {
    offs[0] = 0;
    for (int n = 0; n < NN; ++n) offs[n + 1] = offs[n] + cnt[n];
  }
  if (tid == 1) {
    float cs = 0.f, cd = 0.f;
    for (int f = 0; f < FF; ++f) {
      cs = fmaf(w_gat[f], att_src[f], cs);
      cd = fmaf(w_gat[f], att_dst[f], cd);
    }
    scal_sh[0] = cs;
    scal_sh[1] = cd;
  }
  __syncthreads();
  if (tid < ET) srt[offs[ed] + tk] = es;
  xs[tid] = x_seq[posbase * NN + tid];  // coalesced
  __syncthreads();
  float cs = scal_sh[0], cd = scal_sh[1];
  int p = tid >> 5, n = tid & 31;
  int base = p * 32;
  int e0 = offs[n], e1 = offs[n + 1];
  float xn = xs[base + n];
  float cdxn = cd * xn;
  float m = -3.0e38f;
  for (int e = e0; e < e1; ++e) {
    float ev = fmaf(cs, xs[base + srt[e]], cdxn);
    ev = ev > 0.f ? ev : 0.2f * ev;  // LeakyReLU(0.2)
    m = fmaxf(m, ev);
  }
  float z = 0.f, sa = 0.f;
  for (int e = e0; e < e1; ++e) {
    float xsv = xs[base + srt[e]];
    float ev = fmaf(cs, xsv, cdxn);
    ev = ev > 0.f ? ev : 0.2f * ev;
    float ex = __expf(ev - m);
    z += ex;
    sa = fmaf(ex, xsv, sa);
  }
  sl[p * 32 + n] = sa * frcp(z);
  __syncthreads();
  for (int pp = 0; pp < 8; ++pp) {
    const float4* sp = (const float4*)&sl[pp * 32];
    float a0 = b0, a1 = b1;
#pragma unroll
    for (int q = 0; q < 8; ++q) {
      float4 sv = sp[q];
      a0 = fmaf(sv.x, we0[4 * q], a0);
      a0 = fmaf(sv.y, we0[4 * q + 1], a0);
      a0 = fmaf(sv.z, we0[4 * q + 2], a0);
      a0 = fmaf(sv.w, we0[4 * q + 3], a0);
      a1 = fmaf(sv.x, we1[4 * q], a1);
      a1 = fmaf(sv.y, we1[4 * q + 1], a1);
      a1 = fmaf(sv.z, we1[4 * q + 2], a1);
      a1 = fmaf(sv.w, we1[4 * q + 3], a1);
    }
    size_t row = (size_t)(posbase + pp) * G4;
    xw[row + tid] = a0;
    xw[row + 256 + tid] = a1;
  }
}

// ---------------- LSTM scan: R9 skeleton + gate-split activation ----------------
// R12 NaN root cause: CDNA software-managed hazards. Trans op (v_exp/v_rcp)
// result consumption needs 1 wait state; VALU-write -> DPP-read of the same
// VGPR needs 2. R9's 4-wide act had natural spacing; the scalarized tail
// doesn't. R13 adds the s_nops (5 sites, ~12 cyc/phase).

#define PK16F(HP, W0, W1, W2, W3) \
  "v_pk_fma_f32 v[216:217], v[" HP "], v[" W0 "], 0\n\t" \
  "v_pk_fma_f32 v[218:219], v[" HP "], v[" W1 "], 0\n\t" \
  "v_pk_fma_f32 v[220:221], v[" HP "], v[" W2 "], 0\n\t" \
  "v_pk_fma_f32 v[222:223], v[" HP "], v[" W3 "], 0\n\t"

#define PK16A(HP, W0, W1, W2, W3) \
  "v_pk_fma_f32 v[216:217], v[" HP "], v[" W0 "], v[216:217]\n\t" \
  "v_pk_fma_f32 v[218:219], v[" HP "], v[" W1 "], v[218:219]\n\t" \
  "v_pk_fma_f32 v[220:221], v[" HP "], v[" W2 "], v[220:221]\n\t" \
  "v_pk_fma_f32 v[222:223], v[" HP "], v[" W3 "], v[222:223]\n\t"

#define PHASE(XSLOT, RD, WR) \
  "ds_read_b128 v[32:35], " RD "\n\t" \
  "ds_read_b128 v[36:39], " RD " offset:16\n\t" \
  "ds_read_b128 v[40:43], " RD " offset:32\n\t" \
  "ds_read_b128 v[44:47], " RD " offset:48\n\t" \
  "ds_read_b128 v[48:51], " RD " offset:64\n\t" \
  "ds_read_b128 v[52:55], " RD " offset:80\n\t" \
  "ds_read_b128 v[56:59], " RD " offset:96\n\t" \
  "ds_read_b128 v[60:63], " RD " offset:112\n\t" \
  "s_waitcnt lgkmcnt(7)\n\t" \
  PK16F("32:33", "64:65",  "96:97",   "128:129", "160:161") \
  PK16A("34:35", "66:67",  "98:99",   "130:131", "162:163") \
  "s_waitcnt lgkmcnt(6)\n\t" \
  PK16A("36:37", "68:69",  "100:101", "132:133", "164:165") \
  PK16A("38:39", "70:71",  "102:103", "134:135", "166:167") \
  "s_waitcnt lgkmcnt(5)\n\t" \
  PK16A("40:41", "72:73",  "104:105", "136:137", "168:169") \
  PK16A("42:43", "74:75",  "106:107", "138:139", "170:171") \
  "s_waitcnt lgkmcnt(4)\n\t" \
  PK16A("44:45", "76:77",  "108:109", "140:141", "172:173") \
  PK16A("46:47", "78:79",  "110:111", "142:143", "174:175") \
  "s_waitcnt lgkmcnt(3)\n\t" \
  PK16A("48:49", "80:81",  "112:113", "144:145", "176:177") \
  PK16A("50:51", "82:83",  "114:115", "146:147", "178:179") \
  "s_waitcnt lgkmcnt(2)\n\t" \
  PK16A("52:53", "84:85",  "116:117", "148:149", "180:181") \
  PK16A("54:55", "86:87",  "118:119", "150:151", "182:183") \
  "s_waitcnt lgkmcnt(1)\n\t" \
  PK16A("56:57", "88:89",  "120:121", "152:153", "184:185") \
  PK16A("58:59", "90:91",  "122:123", "154:155", "186:187") \
  "s_waitcnt lgkmcnt(0)\n\t" \
  PK16A("60:61", "92:93",  "124:125", "156:157", "188:189") \
  PK16A("62:63", "94:95",  "126:127", "158:159", "190:191") \
  "s_waitcnt vmcnt(3)\n\t" \
  "v_mov_b32 v215, " XSLOT "\n\t" \
  "global_load_dword " XSLOT ", v194, %[xwb]\n\t" \
  "v_add_u32 v194, 0x800, v194\n\t" \
  "v_add_f32 v204, v216, v217\n\t" \
  "v_add_f32 v205, v218, v219\n\t" \
  "v_add_f32 v206, v220, v221\n\t" \
  "v_add_f32 v207, v222, v223\n\t" \
  "v_add_f32_dpp v204, v204, v204 quad_perm:[1,0,3,2] row_mask:0xf bank_mask:0xf\n\t" \
  "v_add_f32_dpp v205, v205, v205 quad_perm:[1,0,3,2] row_mask:0xf bank_mask:0xf\n\t" \
  "v_add_f32_dpp v206, v206, v206 quad_perm:[1,0,3,2] row_mask:0xf bank_mask:0xf\n\t" \
  "v_add_f32_dpp v207, v207, v207 quad_perm:[1,0,3,2] row_mask:0xf bank_mask:0xf\n\t" \
  "v_add_f32_dpp v204, v204, v204 quad_perm:[2,3,0,1] row_mask:0xf bank_mask:0xf\n\t" \
  "v_add_f32_dpp v205, v205, v205 quad_perm:[2,3,0,1] row_mask:0xf bank_mask:0xf\n\t" \
  "v_add_f32_dpp v206, v206, v206 quad_perm:[2,3,0,1] row_mask:0xf bank_mask:0xf\n\t" \
  "v_add_f32_dpp v207, v207, v207 quad_perm:[2,3,0,1] row_mask:0xf bank_mask:0xf\n\t" \
  "v_cndmask_b32 v208, v204, v205, s[22:23]\n\t" \
  "v_cndmask_b32 v209, v206, v207, s[22:23]\n\t" \
  "v_cndmask_b32 v208, v208, v209, s[24:25]\n\t" \
  "v_add_f32 v208, v208, v215\n\t" \
  "v_mul_f32 v209, v200, v208\n\t" \
  "v_exp_f32 v209, v209\n\t" \
  "s_nop 0\n\t" \
  "v_add_f32 v209, 1.0, v209\n\t" \
  "v_rcp_f32 v209, v209\n\t" \
  "s_nop 0\n\t" \
  "v_fma_f32 v210, v201, v209, v202\n\t" \
  "s_nop 1\n\t" \
  "v_add_f32_dpp v211, v210, v203 quad_perm:[0,0,0,0] row_mask:0xf bank_mask:0xf\n\t" \
  "v_add_f32_dpp v212, v210, v203 quad_perm:[1,1,1,1] row_mask:0xf bank_mask:0xf\n\t" \
  "v_add_f32_dpp v213, v210, v203 quad_perm:[2,2,2,2] row_mask:0xf bank_mask:0xf\n\t" \
  "v_add_f32_dpp v214, v210, v203 quad_perm:[3,3,3,3] row_mask:0xf bank_mask:0xf\n\t" \
  "v_mul_f32 v211, v211, v213\n\t" \
  "v_fma_f32 v199, v212, v199, v211\n\t" \
  "v_mul_f32 v209, 0x4038aa3b, v199\n\t" \
  "v_exp_f32 v209, v209\n\t" \
  "s_nop 0\n\t" \
  "v_add_f32 v209, 1.0, v209\n\t" \
  "v_rcp_f32 v209, v209\n\t" \
  "s_nop 0\n\t" \
  "v_fma_f32 v209, -2.0, v209, 1.0\n\t" \
  "v_mul_f32 v209, v214, v209\n\t" \
  "ds_write_b32 " WR ", v209\n\t" \
  "s_waitcnt lgkmcnt(0)\n\t" \
  "s_barrier\n\t"

__global__ __launch_bounds__(512, 2) void lstm_kernel(const float* __restrict__ xw,
                                                      const float* __restrict__ Wt,
                                                      const float* __restrict__ W_fc,
                                                      const float* __restrict__ b_fc,
                                                      float* __restrict__ out) {
  __shared__ __align__(16) float lds[320];  // hA [0,160) floats, hB [160,320)
  int b = blockIdx.x, tid = threadIdx.x;
  int r = tid >> 2, kq = tid & 3;
  if (tid < 320) lds[tid] = 0.f;
  const float* xwb = xw + (size_t)b * TT * G4;
  unsigned xoff0 = (unsigned)((kq * 128 + r) * 4);  // t=0
  unsigned wtoff = (unsigned)(tid * 512);
  unsigned lbase = (unsigned)(uintptr_t)&lds[0];  // LDS aperture is 4GB-aligned
  unsigned rda = lbase + kq * 160;
  unsigned rdb = rda + 640;
  unsigned wra = lbase + (((r >> 5) * 40 + (r & 31)) << 2);
  unsigned wrb = wra + 640;
  // gate-split act constants: lane kq handles gate kq (i,f,o sigmoid; g=2 tanh)
  float kmulf = (kq == 2) ? __uint_as_float(0x4038aa3bu)   //  2*log2e
                          : __uint_as_float(0xbfb8aa3bu);  // -log2e
  float Af = (kq == 2) ? -2.f : 1.f;
  float Bf = (kq == 2) ? 1.f : 0.f;
  unsigned kqodd = kq & 1, kqhi = kq >> 1;
  __syncthreads();
  asm volatile(
    "v_mov_b32 v194, %[xo]\n\t"
    "v_mov_b32 v195, %[rda]\n\t"
    "v_mov_b32 v196, %[rdb]\n\t"
    "v_mov_b32 v197, %[wra]\n\t"
    "v_mov_b32 v198, %[wrb]\n\t"
    "v_mov_b32 v199, 0\n\t"          // c
    "v_mov_b32 v200, %[km]\n\t"      // kmul
    "v_mov_b32 v201, %[Aa]\n\t"      // A
    "v_mov_b32 v202, %[Bb]\n\t"      // B
    "v_mov_b32 v203, 0\n\t"          // zero (DPP-gather src1)
    "v_cmp_eq_u32 s[22:23], 1, %[kodd]\n\t"
    "v_cmp_eq_u32 s[24:25], 1, %[khi]\n\t"
    // x prefetch ring: t=0..3 -> v224..v227
    "global_load_dword v224, v194, %[xwb]\n\t"
    "v_add_u32 v194, 0x800, v194\n\t"
    "global_load_dword v225, v194, %[xwb]\n\t"
    "v_add_u32 v194, 0x800, v194\n\t"
    "global_load_dword v226, v194, %[xwb]\n\t"
    "v_add_u32 v194, 0x800, v194\n\t"
    "global_load_dword v227, v194, %[xwb]\n\t"
    "v_add_u32 v194, 0x800, v194\n\t"
    "global_load_dwordx4 v[64:67], %[wto], %[wtb] offset:0\n\t"
    "global_load_dwordx4 v[68:71], %[wto], %[wtb] offset:16\n\t"
    "global_load_dwordx4 v[72:75], %[wto], %[wtb] offset:32\n\t"
    "global_load_dwordx4 v[76:79], %[wto], %[wtb] offset:48\n\t"
    "global_load_dwordx4 v[80:83], %[wto], %[wtb] offset:64\n\t"
    "global_load_dwordx4 v[84:87], %[wto], %[wtb] offset:80\n\t"
    "global_load_dwordx4 v[88:91], %[wto], %[wtb] offset:96\n\t"
    "global_load_dwordx4 v[92:95], %[wto], %[wtb] offset:112\n\t"
    "global_load_dwordx4 v[96:99], %[wto], %[wtb] offset:128\n\t"
    "global_load_dwordx4 v[100:103], %[wto], %[wtb] offset:144\n\t"
    "global_load_dwordx4 v[104:107], %[wto], %[wtb] offset:160\n\t"
    "global_load_dwordx4 v[108:111], %[wto], %[wtb] offset:176\n\t"
    "global_load_dwordx4 v[112:115], %[wto], %[wtb] offset:192\n\t"
    "global_load_dwordx4 v[116:119], %[wto], %[wtb] offset:208\n\t"
    "global_load_dwordx4 v[120:123], %[wto], %[wtb] offset:224\n\t"
    "global_load_dwordx4 v[124:127], %[wto], %[wtb] offset:240\n\t"
    "global_load_dwordx4 v[128:131], %[wto], %[wtb] offset:256\n\t"
    "global_load_dwordx4 v[132:135], %[wto], %[wtb] offset:272\n\t"
    "global_load_dwordx4 v[136:139], %[wto], %[wtb] offset:288\n\t"
    "global_load_dwordx4 v[140:143], %[wto], %[wtb] offset:304\n\t"
    "global_load_dwordx4 v[144:147], %[wto], %[wtb] offset:320\n\t"
    "global_load_dwordx4 v[148:151], %[wto], %[wtb] offset:336\n\t"
    "global_load_dwordx4 v[152:155], %[wto], %[wtb] offset:352\n\t"
    "global_load_dwordx4 v[156:159], %[wto], %[wtb] offset:368\n\t"
    "global_load_dwordx4 v[160:163], %[wto], %[wtb] offset:384\n\t"
    "global_load_dwordx4 v[164:167], %[wto], %[wtb] offset:400\n\t"
    "global_load_dwordx4 v[168:171], %[wto], %[wtb] offset:416\n\t"
    "global_load_dwordx4 v[172:175], %[wto], %[wtb] offset:432\n\t"
    "global_load_dwordx4 v[176:179], %[wto], %[wtb] offset:448\n\t"
    "global_load_dwordx4 v[180:183], %[wto], %[wtb] offset:464\n\t"
    "global_load_dwordx4 v[184:187], %[wto], %[wtb] offset:480\n\t"
    "global_load_dwordx4 v[188:191], %[wto], %[wtb] offset:496\n\t"
    "s_waitcnt vmcnt(0)\n\t"
    "s_movk_i32 s20, 0x80\n\t"    // 128 iterations x 4 phases = 512 steps
    "L_lstm_%=:\n\t"
    PHASE("v224", "v195", "v198")   // t%4==0: read A, write B
    PHASE("v225", "v196", "v197")   // t%4==1: read B, write A
    PHASE("v226", "v195", "v198")   // t%4==2: read A, write B
    PHASE("v227", "v196", "v197")   // t%4==3: read B, write A
    "s_sub_u32 s20, s20, 1\n\t"
    "s_cmp_lg_u32 s20, 0\n\t"
    "s_cbranch_scc1 L_lstm_%=\n\t"
    "s_waitcnt vmcnt(0) lgkmcnt(0)\n\t"
    :
    : [xwb]"s"(xwb), [wtb]"s"(Wt), [wto]"v"(wtoff), [xo]"v"(xoff0),
      [rda]"v"(rda), [rdb]"v"(rdb), [wra]"v"(wra), [wrb]"v"(wrb),
      [km]"v"(kmulf), [Aa]"v"(Af), [Bb]"v"(Bf),
      [kodd]"v"(kqodd), [khi]"v"(kqhi)
    : "memory", "scc", "s20", "s22", "s23", "s24", "s25",
      "v32","v33","v34","v35","v36","v37","v38","v39",
      "v40","v41","v42","v43","v44","v45","v46","v47",
      "v48","v49","v50","v51","v52","v53","v54","v55",
      "v56","v57","v58","v59","v60","v61","v62","v63",
      "v64","v65","v66","v67","v68","v69","v70","v71",
      "v72","v73","v74","v75","v76","v77","v78","v79",
      "v80","v81","v82","v83","v84","v85","v86","v87",
      "v88","v89","v90","v91","v92","v93","v94","v95",
      "v96","v97","v98","v99","v100","v101","v102","v103",
      "v104","v105","v106","v107","v108","v109","v110","v111",
      "v112","v113","v114","v115","v116","v117","v118","v119",
      "v120","v121","v122","v123","v124","v125","v126","v127",
      "v128","v129","v130","v131","v132","v133","v134","v135",
      "v136","v137","v138","v139","v140","v141","v142","v143",
      "v144","v145","v146","v147","v148","v149","v150","v151",
      "v152","v153","v154","v155","v156","v157","v158","v159",
      "v160","v161","v162","v163","v164","v165","v166","v167",
      "v168","v169","v170","v171","v172","v173","v174","v175",
      "v176","v177","v178","v179","v180","v181","v182","v183",
      "v184","v185","v186","v187","v188","v189","v190","v191",
      "v192","v193","v194","v195","v196","v197","v198","v199",
      "v200","v201","v202","v203","v204","v205","v206","v207",
      "v208","v209","v210","v211","v212","v213","v214","v215",
      "v216","v217","v218","v219","v220","v221","v222","v223",
      "v224","v225","v226","v227");
  __syncthreads();
  // final h (after t=511) is in buffer A: lds[(k>>5)*40 + (k&31)]
  if (tid < 4) {
    float acc = b_fc[tid];
#pragma unroll 8
    for (int k = 0; k < HH; ++k)
      acc = fmaf(lds[(k >> 5) * 40 + (k & 31)], W_fc[k * 4 + tid], acc);
    out[b * 4 + tid] = acc;
  }
}

extern "C" void kernel_launch(void* const* d_in, const int* in_sizes, int n_in,
                              void* d_out, int out_size, void* d_ws, size_t ws_size,
                              hipStream_t stream) {
  const float* x_seq   = (const float*)d_in[0];
  const int*   ei      = (const int*)d_in[1];
  const float* w_gat   = (const float*)d_in[2];
  const float* att_src = (const float*)d_in[3];
  const float* att_dst = (const float*)d_in[4];
  const float* b_gat   = (const float*)d_in[5];
  const float* W_ih    = (const float*)d_in[6];
  const float* W_hh    = (const float*)d_in[7];
  const float* b_ih    = (const float*)d_in[8];
  const float* b_hh    = (const float*)d_in[9];
  const float* W_fc    = (const float*)d_in[10];
  const float* b_fc    = (const float*)d_in[11];

  float* ws = (float*)d_ws;
  float* Wt    = ws;                            // 512*128 = 65536 f (16B-aligned)
  float* xw    = Wt + 65536;                    // (16384+8)*512 f (pad rows: 4-deep prefetch)
  float* W_eff = xw + (size_t)(NPOS + 8) * G4;  // 32*512
  float* biasp = W_eff + NN * G4;               // 32*512

  prep_kernel<<<NN, G4, 0, stream>>>(w_gat, b_gat, W_ih, W_hh, W_eff, biasp, Wt);
  gatxw_kernel<<<NPOS / 8, 256, 0, stream>>>(x_seq, ei, w_gat, att_src, att_dst,
                                             b_ih, b_hh, W_eff, biasp, xw);
  lstm_kernel<<<BB, G4, 0, stream>>>(xw, Wt, W_fc, b_fc, (float*)d_out);
}